// Round 14
// baseline (326.935 us; speedup 1.0000x reference)
//
#include <hip/hip_runtime.h>
#include <math.h>

// ---------------------------------------------------------------------------
// R14 = R13 + algebraic elimination of L3:
//   ctx = h2@cx_w3 + cx_b3 is LINEAR and consumed only by P7's two linear
//   GEMMs, so fold: W_t1 = cx_w3@atc_w1, b_t1 = cx_b3@atc_w1 + atc_b1,
//   W_P = cx_w3@as_w1[:128], b_P = cx_b3@as_w1. Precomputed per-launch into
//   d_ws by the (expanded, 1024-thread) precompute kernel. Big-layer chain
//   4 -> 3, one fewer barrier. P9 g-loop unroll 2 -> 4 (R13-validated axis).
// Core structure (R8/R10/R13): grid 256, MT=64, 1024 threads (16 waves) —
// occupancy ceiling for lane=row design. Wave-uniform s_load weights +
// SGPR-operand FMA; quad-packed activations buf[(c>>2)*256 + r*4 + (c&3)].
// NO min-waves launch bound (R4: clamps VGPR -> spills).
// ws layout (floats): [0:1920) Qa | [1920:1950) strength | [1950:1980) hasv |
//   [2048:10240) W_t1 128x64 | [10240:10304) b_t1 |
//   [10304:18496) W_P 128x64 | [18496:18560) b_P     (~74 KB)
// ---------------------------------------------------------------------------

__device__ __forceinline__ void encode_card32(int c,
                                              const float* __restrict__ val_emb,
                                              const float* __restrict__ suit_emb,
                                              const float* __restrict__ type_emb,
                                              float* e) {
  bool inv = (c == 0) || (c == 53);
  int v = inv ? 0 : ((c - 1) % 13 + 1);
  int s = inv ? 0 : ((c - 1) / 13 + 1);
  int ct = (v == 11) ? 1 : (v == 12) ? 2 : (v == 13) ? 3 : 0;
#pragma unroll
  for (int i = 0; i < 16; ++i) e[i] = val_emb[v * 16 + i];
#pragma unroll
  for (int i = 0; i < 16; ++i) e[16 + i] = suit_emb[s * 16 + i];
#pragma unroll
  for (int i = 0; i < 8; ++i) e[i] += type_emb[ct * 8 + i];
}

// ---------------------------------------------------------------------------
// Kernel 1: per-launch precompute, 1 block x 1024 threads.
//  - action features + Qa (as before)
//  - fused L3/P7 weights: W_t1 = cx_w3@atc_w1 (+b), W_P = cx_w3@as_w1 (+b)
// ---------------------------------------------------------------------------
__global__ __launch_bounds__(1024) void precompute_kernel(
    const int* __restrict__ acards,
    const float* __restrict__ val_emb, const float* __restrict__ suit_emb,
    const float* __restrict__ type_emb,
    const float* __restrict__ ce_w1, const float* __restrict__ ce_b1,
    const float* __restrict__ ce_w2, const float* __restrict__ ce_b2,
    const float* __restrict__ as_w1, const float* __restrict__ as_b1,
    const float* __restrict__ cx_w3, const float* __restrict__ cx_b3,
    const float* __restrict__ atc_w1, const float* __restrict__ atc_b1,
    float* __restrict__ ws) {
  __shared__ float sAct[30][32];
  __shared__ float sCombo[30][16];
  const int tid = threadIdx.x;

  if (tid < 30) {
    int c[4];
#pragma unroll
    for (int i = 0; i < 4; ++i) c[i] = acards[tid * 4 + i];
    bool mask[4]; int vals[4], suits[4]; int csize = 0; bool hasv = false;
#pragma unroll
    for (int i = 0; i < 4; ++i) {
      mask[i] = (c[i] != 0);
      if (mask[i]) { csize++; hasv = true; }
      vals[i] = mask[i] ? ((c[i] - 1) % 13 + 1) : 0;
      suits[i] = mask[i] ? ((c[i] - 1) / 13 + 1) : 0;
    }
    int fvv = mask[0] ? vals[0] : mask[1] ? vals[1] : mask[2] ? vals[2]
              : mask[3] ? vals[3] : vals[0];
    bool same = true;
#pragma unroll
    for (int i = 0; i < 4; ++i) if (mask[i] && vals[i] != fvv) same = false;
    float total = 0.f;
#pragma unroll
    for (int i = 0; i < 4; ++i) {
      if (mask[i]) {
        int v = vals[i];
        total += (v == 1) ? 1.f : (v == 11) ? 10.f : (v == 12) ? 15.f
                 : (v == 13) ? 20.f : (float)v;
      }
    }
    float uniq = 0.f;
#pragma unroll
    for (int s = 1; s <= 4; ++s) {
      bool any = false;
#pragma unroll
      for (int i = 0; i < 4; ++i) if (suits[i] == s) any = true;
      uniq += any ? 1.f : 0.f;
    }
    bool ace = false;
#pragma unroll
    for (int i = 0; i < 4; ++i) if (mask[i] && vals[i] == 1) ace = true;
    float f_same = same ? 1.f : 0.f, f_ace = ace ? 1.f : 0.f;
    float valid = (((float)csize <= 4.f) && (f_same > 0.f || f_ace > 0.f)) ? 1.f : 0.f;
    float feats[6] = {(float)csize, f_same, total, uniq, f_ace, valid};
    if (!hasv) { for (int i = 0; i < 6; ++i) feats[i] = 0.f; }
    float emb[32];
#pragma unroll
    for (int i = 0; i < 32; ++i) emb[i] = 0.f;
    float cnt = 0.f;
#pragma unroll
    for (int i = 0; i < 4; ++i) {
      float e[32];
      encode_card32(c[i], val_emb, suit_emb, type_emb, e);
      if (mask[i]) {
#pragma unroll
        for (int j = 0; j < 32; ++j) emb[j] += e[j];
        cnt += 1.f;
      }
    }
    float invc = 1.f / fmaxf(cnt, 1.f);
#pragma unroll
    for (int j = 0; j < 32; ++j) sAct[tid][j] = hasv ? emb[j] * invc : 0.f;
    float t32[32];
#pragma unroll
    for (int j = 0; j < 32; ++j) {
      float acc = ce_b1[j];
#pragma unroll
      for (int k = 0; k < 6; ++k) acc += feats[k] * ce_w1[k * 32 + j];
      t32[j] = fmaxf(acc, 0.f);
    }
#pragma unroll
    for (int j = 0; j < 16; ++j) {
      float acc = ce_b2[j];
#pragma unroll
      for (int k = 0; k < 32; ++k) acc += t32[k] * ce_w2[k * 16 + j];
      sCombo[tid][j] = acc;
    }
    ws[1920 + tid] = total * 0.05f;
    ws[1950 + tid] = hasv ? 1.f : 0.f;
  }

  // fused weights (no shared-mem dependency): W_t1 / W_P
  for (int idx = tid; idx < 8192; idx += 1024) {
    int k = idx >> 6, j = idx & 63;
    float at = 0.f, ap = 0.f;
#pragma unroll 4
    for (int m = 0; m < 128; ++m) {
      float c = cx_w3[k * 128 + m];
      at += c * atc_w1[m * 64 + j];
      ap += c * as_w1[(size_t)m * 64 + j];
    }
    ws[2048 + idx] = at;
    ws[10304 + idx] = ap;
  }
  if (tid < 64) {
    float bt = atc_b1[tid], bp = 0.f;
#pragma unroll 4
    for (int m = 0; m < 128; ++m) {
      float c = cx_b3[m];
      bt += c * atc_w1[m * 64 + tid];
      bp += c * as_w1[(size_t)m * 64 + tid];
    }
    ws[10240 + tid] = bt;
    ws[18496 + tid] = bp;
  }

  __syncthreads();
  for (int idx = tid; idx < 1920; idx += 1024) {
    int a = idx >> 6, j = idx & 63;
    float acc = as_b1[j];
#pragma unroll
    for (int k = 0; k < 32; ++k) acc += sAct[a][k] * as_w1[(128 + k) * 64 + j];
#pragma unroll
    for (int k = 0; k < 16; ++k) acc += sCombo[a][k] * as_w1[(160 + k) * 64 + j];
    ws[idx] = acc;
  }
}

// ---------------------------------------------------------------------------
// Unified layer: QIN = quad-packed input (ds_read_b128, 4 k per read),
// else simple [k][64]. QOUT = quad-packed output. W read wave-uniformly.
// QIN loop unrolled x8 (32 k-values of scalar prefetch in flight).
// ---------------------------------------------------------------------------
template <int K, int NJ, bool RELU, bool HASB, bool QIN, bool QOUT>
__device__ __forceinline__ void layerU(
    const float* __restrict__ in, int inColBase, float* __restrict__ outB,
    int outColBase, const float* __restrict__ W, int ldw, int j0,
    const float* __restrict__ bias, int r) {
  float acc[NJ];
#pragma unroll
  for (int j = 0; j < NJ; ++j) acc[j] = HASB ? bias[j0 + j] : 0.f;
  if constexpr (QIN) {
    static_assert(K % 4 == 0, "quad input needs K%4==0");
    const int g0 = inColBase >> 2;
#pragma unroll 8
    for (int g = 0; g < K / 4; ++g) {
      float4 a = *(const float4*)&in[(g0 + g) * 256 + r * 4];
#pragma unroll
      for (int q = 0; q < 4; ++q) {
        float av = (q == 0) ? a.x : (q == 1) ? a.y : (q == 2) ? a.z : a.w;
        const float* wr = W + (size_t)(g * 4 + q) * ldw + j0;
#pragma unroll
        for (int j = 0; j < NJ; ++j) acc[j] += av * wr[j];
      }
    }
  } else {
#pragma unroll 4
    for (int k = 0; k < K; ++k) {
      float a = in[(inColBase + k) * 64 + r];
      const float* wr = W + (size_t)k * ldw + j0;
#pragma unroll
      for (int j = 0; j < NJ; ++j) acc[j] += a * wr[j];
    }
  }
#pragma unroll
  for (int j = 0; j < NJ; ++j) if (RELU) acc[j] = fmaxf(acc[j], 0.f);
  if constexpr (QOUT && (NJ % 4 == 0)) {
    const int c0 = outColBase + j0;      // quad-aligned by construction
#pragma unroll
    for (int qg = 0; qg < NJ / 4; ++qg) {
      float4 o = make_float4(acc[qg * 4], acc[qg * 4 + 1],
                             acc[qg * 4 + 2], acc[qg * 4 + 3]);
      *(float4*)&outB[((c0 >> 2) + qg) * 256 + r * 4] = o;
    }
  } else {
#pragma unroll
    for (int j = 0; j < NJ; ++j) outB[(outColBase + j0 + j) * 64 + r] = acc[j];
  }
}

// ---------------------------------------------------------------------------
// Main kernel. 64 rows/block, 1024 threads (16 waves), grid 256.
// bufA (quad, 152 cols): [0:32) hand_ctx | [32:64) enemy | [64:96) strat_ctx |
//   [96:150) discard -> later h2 (128)
// bufB: rows [0:20) strat_in | [20:84) t64 | [84:116) V | 116 sLen
//   -> later quad h1 -> later P7 out: t1 quads 0..15 | P quads 16..31
// ---------------------------------------------------------------------------
__global__ __launch_bounds__(1024) void policy_main(
    const int* __restrict__ hand_cards, const int* __restrict__ enemy_card,
    const int* __restrict__ hand_size, const float* __restrict__ game_state,
    const float* __restrict__ discard,
    const float* __restrict__ val_emb, const float* __restrict__ suit_emb,
    const float* __restrict__ type_emb,
    const float* __restrict__ he_wv, const float* __restrict__ he_bv,
    const float* __restrict__ he_wo, const float* __restrict__ he_bo,
    const float* __restrict__ se_w1, const float* __restrict__ se_b1,
    const float* __restrict__ se_w2, const float* __restrict__ se_b2,
    const float* __restrict__ atc_w2, const float* __restrict__ atc_b2,
    const float* __restrict__ as_w2, const float* __restrict__ as_b2,
    const float* __restrict__ as_w3, const float* __restrict__ as_b3,
    const float* __restrict__ cx_w1, const float* __restrict__ cx_b1,
    const float* __restrict__ cx_w2, const float* __restrict__ cx_b2,
    const float* __restrict__ ws, float* __restrict__ out) {
  __shared__ float bufA[38 * 256];   // 38 quad groups = 152 cols, 38 KB
  __shared__ float bufB[128 * 64];   // 32 KB

  const int tid = threadIdx.x;
  const int r = tid & 63;                                   // lane = batch row
  const int wq = __builtin_amdgcn_readfirstlane(tid >> 6);  // wave id 0..15
  const int b0 = blockIdx.x * 64;

  // ---------------- P0: staging + per-row features --------------------------
  for (int idx = tid; idx < 64 * 54; idx += 1024) {          // discard -> bufA
    int rr = idx / 54, k = idx - rr * 54;
    int c = 96 + k;
    bufA[(c >> 2) * 256 + rr * 4 + (c & 3)] = discard[(size_t)b0 * 54 + idx];
  }
  if (wq == 2) {                                            // game_state rows 0..9
#pragma unroll
    for (int k = 0; k < 10; ++k)
      bufB[k * 64 + r] = game_state[(size_t)(b0 + r) * 10 + k];
  }
  if (wq == 0) {                                            // hand features rows 10..19
    const int b = b0 + r;
    const float hsz = (float)hand_size[b];
    int aces = 0, faces = 0, low = 0, c1 = 0, c2 = 0, c3 = 0, c4 = 0;
#pragma unroll
    for (int i = 0; i < 8; ++i) {
      int c = hand_cards[b * 8 + i];
      int v = (c == 0) ? 0 : ((c - 1) % 13 + 1);
      int s = (c == 0) ? 0 : ((c - 1) / 13 + 1);
      aces += (v == 1);
      faces += (v >= 11 && v <= 13);
      low += (v >= 2 && v <= 6);
      c1 += (s == 1); c2 += (s == 2); c3 += (s == 3); c4 += (s == 4);
    }
    float sdiv = (float)((c1 > 0) + (c2 > 0) + (c3 > 0) + (c4 > 0)) * 0.25f;
    float hvr = (float)faces / (hsz + 1e-8f);
    bufB[(10 + 0) * 64 + r] = hsz;          bufB[(10 + 1) * 64 + r] = (float)aces;
    bufB[(10 + 2) * 64 + r] = (float)faces; bufB[(10 + 3) * 64 + r] = (float)low;
    bufB[(10 + 4) * 64 + r] = (float)c1;    bufB[(10 + 5) * 64 + r] = (float)c2;
    bufB[(10 + 6) * 64 + r] = (float)c3;    bufB[(10 + 7) * 64 + r] = (float)c4;
    bufB[(10 + 8) * 64 + r] = hvr;          bufB[(10 + 9) * 64 + r] = sdiv;
  }
  if (wq == 1) {                                            // enemy (quad) + sLen
    const int b = b0 + r;
    bufB[116 * 64 + r] = 8.0f / fmaxf((float)hand_size[b], 1.0f);
    float e[32];
    encode_card32(enemy_card[b], val_emb, suit_emb, type_emb, e);
#pragma unroll
    for (int g = 0; g < 8; ++g) {
      float4 ev = make_float4(e[g * 4], e[g * 4 + 1], e[g * 4 + 2], e[g * 4 + 3]);
      *(float4*)&bufA[(8 + g) * 256 + r * 4] = ev;   // cols 32..63
    }
  }
  __syncthreads();

  // ---------------- Phase A (task-parallel): se L1 | V -----------------------
  if (wq < 8) {
    layerU<20, 8, true, true, false, false>(bufB, 0, bufB, 20, se_w1, 64,
                                            wq * 8, se_b1, r);
  } else {
    layerU<32, 4, false, true, true, false>(bufA, 32, bufB, 84, he_wv, 32,
                                            (wq - 8) * 4, he_bv, r);
  }
  __syncthreads();

  // ---------------- Phase B (task-parallel): se L2 | hand_ctx ----------------
  if (wq < 8) {
    layerU<64, 4, false, true, false, true>(bufB, 20, bufA, 64, se_w2, 32,
                                            wq * 4, se_b2, r);
  } else {
    const int j0 = (wq - 8) * 4;
    float acc[4];
#pragma unroll
    for (int j = 0; j < 4; ++j) acc[j] = he_bo[j0 + j];
#pragma unroll 4
    for (int k = 0; k < 32; ++k) {
      float a = bufB[(84 + k) * 64 + r];
      const float* wr = he_wo + (size_t)k * 32 + j0;
#pragma unroll
      for (int j = 0; j < 4; ++j) acc[j] += a * wr[j];
    }
    float scale = bufB[116 * 64 + r];
    float4 o = make_float4(scale * acc[0], scale * acc[1],
                           scale * acc[2], scale * acc[3]);
    *(float4*)&bufA[(j0 >> 2) * 256 + r * 4] = o;
  }
  __syncthreads();

  // ---------------- L1: 150->128 relu, all input in LDS (37 quads + tail) ----
  {
    const int j0 = wq * 8;
    float acc[8];
#pragma unroll
    for (int j = 0; j < 8; ++j) acc[j] = cx_b1[j0 + j];
#pragma unroll 8
    for (int g = 0; g < 37; ++g) {
      float4 a = *(const float4*)&bufA[g * 256 + r * 4];
#pragma unroll
      for (int q = 0; q < 4; ++q) {
        float av = (q == 0) ? a.x : (q == 1) ? a.y : (q == 2) ? a.z : a.w;
        const float* wr = cx_w1 + (size_t)(g * 4 + q) * 128 + j0;
#pragma unroll
        for (int j = 0; j < 8; ++j) acc[j] += av * wr[j];
      }
    }
    {  // tail: cols 148,149 (discard elements 52,53)
      float4 a = *(const float4*)&bufA[37 * 256 + r * 4];
      const float* wr0 = cx_w1 + (size_t)148 * 128 + j0;
      const float* wr1 = cx_w1 + (size_t)149 * 128 + j0;
#pragma unroll
      for (int j = 0; j < 8; ++j) acc[j] += a.x * wr0[j] + a.y * wr1[j];
    }
#pragma unroll
    for (int qg = 0; qg < 2; ++qg) {
      float4 o = make_float4(fmaxf(acc[qg * 4], 0.f), fmaxf(acc[qg * 4 + 1], 0.f),
                             fmaxf(acc[qg * 4 + 2], 0.f), fmaxf(acc[qg * 4 + 3], 0.f));
      *(float4*)&bufB[((j0 >> 2) + qg) * 256 + r * 4] = o;   // h1 quad
    }
  }
  __syncthreads();

  // ---------------- L2: 128->128 relu  (bufB quad -> bufA quad = h2) --------
  layerU<128, 8, true, true, true, true>(bufB, 0, bufA, 0, cx_w2, 128, wq * 8,
                                         cx_b2, r);
  __syncthreads();

  // ---------------- P7 (L3 folded): t1 | P from h2  (bufA -> bufB) ----------
  if (wq < 8) {
    layerU<128, 8, true, true, true, true>(bufA, 0, bufB, 0, ws + 2048, 64,
                                           wq * 8, ws + 10240, r);
  } else {
    layerU<128, 8, false, true, true, true>(bufA, 0, bufB, 64, ws + 10304, 64,
                                            (wq - 8) * 8, ws + 18496, r);
  }
  __syncthreads();

  // ---------------- P9: scoring (logits per-wave from t1; P from bufB) ------
  if (wq < 15) {
    float lg0 = atc_b2[0], lg1 = atc_b2[1], lg2 = atc_b2[2], lg3 = atc_b2[3];
#pragma unroll 4
    for (int g = 0; g < 16; ++g) {            // t1 = bufB quad groups 0..15
      float4 t = *(const float4*)&bufB[g * 256 + r * 4];
#pragma unroll
      for (int q = 0; q < 4; ++q) {
        float tv = (q == 0) ? t.x : (q == 1) ? t.y : (q == 2) ? t.z : t.w;
        const float* wr = atc_w2 + (size_t)(g * 4 + q) * 4;
        lg0 += tv * wr[0]; lg1 += tv * wr[1];
        lg2 += tv * wr[2]; lg3 += tv * wr[3];
      }
    }
    float m = fmaxf(fmaxf(lg0, lg1), fmaxf(lg2, lg3));
    float e0 = expf(lg0 - m), e1 = expf(lg1 - m), e2 = expf(lg2 - m), e3 = expf(lg3 - m);
    float inv = 1.f / (e0 + e1 + e2 + e3);
    float tp0 = e0 * inv, tp1 = e1 * inv, tp3 = e3 * inv;

    const float b3v = as_b3[0];
#pragma unroll 1
    for (int i = 0; i < 2; ++i) {
      const int a = wq * 2 + i;                // wave-uniform
      const float* qa = ws + a * 64;           // uniform -> s_load
      float acc[32];
#pragma unroll
      for (int j = 0; j < 32; ++j) acc[j] = 0.f;
#pragma unroll 4
      for (int g = 0; g < 16; ++g) {           // P = bufB quad groups 16..31
        float4 pv = *(const float4*)&bufB[(16 + g) * 256 + r * 4];
#pragma unroll
        for (int q = 0; q < 4; ++q) {
          float p = (q == 0) ? pv.x : (q == 1) ? pv.y : (q == 2) ? pv.z : pv.w;
          const int k = g * 4 + q;
          float s = fmaxf(p + qa[k], 0.f);
          const float* w2r = as_w2 + (size_t)k * 32;
#pragma unroll
          for (int j = 0; j < 32; ++j) acc[j] += s * w2r[j];
        }
      }
      float sc = b3v;
#pragma unroll
      for (int j = 0; j < 32; ++j)
        sc += fmaxf(acc[j] + as_b2[j], 0.f) * as_w3[j];
      float st = ws[1920 + a], hv = ws[1950 + a];
      float bon = (hv > 0.5f) ? (tp0 * st + tp1 * (1.f - st)) : tp3 * 2.f;
      out[(size_t)(b0 + r) * 30 + a] = sc + bon;
    }
  }
}

// ---------------------------------------------------------------------------
extern "C" void kernel_launch(void* const* d_in, const int* in_sizes, int n_in,
                              void* d_out, int out_size, void* d_ws, size_t ws_size,
                              hipStream_t stream) {
  (void)in_sizes; (void)n_in; (void)out_size; (void)ws_size;
  const int* hand_cards = (const int*)d_in[0];
  const int* enemy_card = (const int*)d_in[1];
  const int* hand_size = (const int*)d_in[2];
  const float* game_state = (const float*)d_in[3];
  const float* discard = (const float*)d_in[4];
  const int* acards = (const int*)d_in[5];
  // d_in[6] = num_valid_actions (unused scalar)
  const float* val_emb = (const float*)d_in[7];
  const float* suit_emb = (const float*)d_in[8];
  const float* type_emb = (const float*)d_in[9];
  const float* ce_w1 = (const float*)d_in[10], * ce_b1 = (const float*)d_in[11];
  const float* ce_w2 = (const float*)d_in[12], * ce_b2 = (const float*)d_in[13];
  // d_in[14..21] = ha_* (hand self-attention) -- provably dead code, unused
  const float* he_wv = (const float*)d_in[26], * he_bv = (const float*)d_in[27];
  const float* he_wo = (const float*)d_in[28], * he_bo = (const float*)d_in[29];
  const float* se_w1 = (const float*)d_in[30], * se_b1 = (const float*)d_in[31];
  const float* se_w2 = (const float*)d_in[32], * se_b2 = (const float*)d_in[33];
  const float* atc_w1 = (const float*)d_in[34], * atc_b1 = (const float*)d_in[35];
  const float* atc_w2 = (const float*)d_in[36], * atc_b2 = (const float*)d_in[37];
  const float* as_w1 = (const float*)d_in[38], * as_b1 = (const float*)d_in[39];
  const float* as_w2 = (const float*)d_in[40], * as_b2 = (const float*)d_in[41];
  const float* as_w3 = (const float*)d_in[42], * as_b3 = (const float*)d_in[43];
  const float* cx_w1 = (const float*)d_in[44], * cx_b1 = (const float*)d_in[45];
  const float* cx_w2 = (const float*)d_in[46], * cx_b2 = (const float*)d_in[47];
  const float* cx_w3 = (const float*)d_in[48], * cx_b3 = (const float*)d_in[49];
  float* ws = (float*)d_ws;
  float* out = (float*)d_out;

  hipLaunchKernelGGL(precompute_kernel, dim3(1), dim3(1024), 0, stream,
                     acards, val_emb, suit_emb, type_emb,
                     ce_w1, ce_b1, ce_w2, ce_b2, as_w1, as_b1,
                     cx_w3, cx_b3, atc_w1, atc_b1, ws);
  hipLaunchKernelGGL(policy_main, dim3(256), dim3(1024), 0, stream,
                     hand_cards, enemy_card, hand_size, game_state, discard,
                     val_emb, suit_emb, type_emb,
                     he_wv, he_bv, he_wo, he_bo,
                     se_w1, se_b1, se_w2, se_b2,
                     atc_w2, atc_b2,
                     as_w2, as_b2, as_w3, as_b3,
                     cx_w1, cx_b1, cx_w2, cx_b2,
                     ws, out);
}

// Round 15
// 238.809 us; speedup vs baseline: 1.3690x; 1.3690x over previous
//
#include <hip/hip_runtime.h>
#include <math.h>

// ---------------------------------------------------------------------------
// R15 = R14 with the precompute PARALLELIZED (R14's fold was right but ran
// the 128x64x128x2 fused-weight GEMM on ONE block/CU -> 100 us latency-bound
// prologue, 255 CUs idle). Now grid 33 x 256: block 0 = action features +
// Qa + fused biases; blocks 1..32 = 256 W-entries each (1/thread,
// j-coalesced, 128 MACs) -> ~5 us.
// Main kernel (unchanged from R14): L3 folded into P7 via
//   W_t1 = cx_w3@atc_w1, b_t1 = cx_b3@atc_w1 + atc_b1,
//   W_P  = cx_w3@as_w1[:128], b_P = cx_b3@as_w1.
// Core structure (R8/R13): grid 256, MT=64, 1024 threads (16 waves),
// wave-uniform s_load weights + SGPR-operand FMA, quad-packed activations
// buf[(c>>2)*256 + r*4 + (c&3)]. NO min-waves launch bound (R4: spills).
// ws layout (floats): [0:1920) Qa | [1920:1950) strength | [1950:1980) hasv |
//   [2048:10240) W_t1 | [10240:10304) b_t1 | [10304:18496) W_P | [18496:18560) b_P
// ---------------------------------------------------------------------------

__device__ __forceinline__ void encode_card32(int c,
                                              const float* __restrict__ val_emb,
                                              const float* __restrict__ suit_emb,
                                              const float* __restrict__ type_emb,
                                              float* e) {
  bool inv = (c == 0) || (c == 53);
  int v = inv ? 0 : ((c - 1) % 13 + 1);
  int s = inv ? 0 : ((c - 1) / 13 + 1);
  int ct = (v == 11) ? 1 : (v == 12) ? 2 : (v == 13) ? 3 : 0;
#pragma unroll
  for (int i = 0; i < 16; ++i) e[i] = val_emb[v * 16 + i];
#pragma unroll
  for (int i = 0; i < 16; ++i) e[16 + i] = suit_emb[s * 16 + i];
#pragma unroll
  for (int i = 0; i < 8; ++i) e[i] += type_emb[ct * 8 + i];
}

// ---------------------------------------------------------------------------
// Precompute, grid 33 x 256.
//  block 0:   action features + Qa + fused biases b_t1/b_P
//  blocks 1+: W_t1/W_P entries, idx = (bid-1)*256 + tid
// ---------------------------------------------------------------------------
__global__ __launch_bounds__(256) void precompute_kernel(
    const int* __restrict__ acards,
    const float* __restrict__ val_emb, const float* __restrict__ suit_emb,
    const float* __restrict__ type_emb,
    const float* __restrict__ ce_w1, const float* __restrict__ ce_b1,
    const float* __restrict__ ce_w2, const float* __restrict__ ce_b2,
    const float* __restrict__ as_w1, const float* __restrict__ as_b1,
    const float* __restrict__ cx_w3, const float* __restrict__ cx_b3,
    const float* __restrict__ atc_w1, const float* __restrict__ atc_b1,
    float* __restrict__ ws) {
  const int tid = threadIdx.x;
  const int bid = blockIdx.x;

  if (bid > 0) {
    // fused weights: one (k,j) entry per thread, j coalesced
    const int idx = (bid - 1) * 256 + tid;
    const int k = idx >> 6, j = idx & 63;
    float at = 0.f, ap = 0.f;
#pragma unroll 8
    for (int m = 0; m < 128; ++m) {
      float c = cx_w3[k * 128 + m];
      at += c * atc_w1[m * 64 + j];
      ap += c * as_w1[(size_t)m * 64 + j];
    }
    ws[2048 + idx] = at;
    ws[10304 + idx] = ap;
    return;
  }

  // ----- block 0: biases + action features + Qa -----
  __shared__ float sAct[30][32];
  __shared__ float sCombo[30][16];

  if (tid >= 64 && tid < 128) {
    const int j = tid - 64;
    float bt = atc_b1[j], bp = 0.f;
#pragma unroll 8
    for (int m = 0; m < 128; ++m) {
      float c = cx_b3[m];
      bt += c * atc_w1[m * 64 + j];
      bp += c * as_w1[(size_t)m * 64 + j];
    }
    ws[10240 + j] = bt;
    ws[18496 + j] = bp;
  }

  if (tid < 30) {
    int c[4];
#pragma unroll
    for (int i = 0; i < 4; ++i) c[i] = acards[tid * 4 + i];
    bool mask[4]; int vals[4], suits[4]; int csize = 0; bool hasv = false;
#pragma unroll
    for (int i = 0; i < 4; ++i) {
      mask[i] = (c[i] != 0);
      if (mask[i]) { csize++; hasv = true; }
      vals[i] = mask[i] ? ((c[i] - 1) % 13 + 1) : 0;
      suits[i] = mask[i] ? ((c[i] - 1) / 13 + 1) : 0;
    }
    int fvv = mask[0] ? vals[0] : mask[1] ? vals[1] : mask[2] ? vals[2]
              : mask[3] ? vals[3] : vals[0];
    bool same = true;
#pragma unroll
    for (int i = 0; i < 4; ++i) if (mask[i] && vals[i] != fvv) same = false;
    float total = 0.f;
#pragma unroll
    for (int i = 0; i < 4; ++i) {
      if (mask[i]) {
        int v = vals[i];
        total += (v == 1) ? 1.f : (v == 11) ? 10.f : (v == 12) ? 15.f
                 : (v == 13) ? 20.f : (float)v;
      }
    }
    float uniq = 0.f;
#pragma unroll
    for (int s = 1; s <= 4; ++s) {
      bool any = false;
#pragma unroll
      for (int i = 0; i < 4; ++i) if (suits[i] == s) any = true;
      uniq += any ? 1.f : 0.f;
    }
    bool ace = false;
#pragma unroll
    for (int i = 0; i < 4; ++i) if (mask[i] && vals[i] == 1) ace = true;
    float f_same = same ? 1.f : 0.f, f_ace = ace ? 1.f : 0.f;
    float valid = (((float)csize <= 4.f) && (f_same > 0.f || f_ace > 0.f)) ? 1.f : 0.f;
    float feats[6] = {(float)csize, f_same, total, uniq, f_ace, valid};
    if (!hasv) { for (int i = 0; i < 6; ++i) feats[i] = 0.f; }
    float emb[32];
#pragma unroll
    for (int i = 0; i < 32; ++i) emb[i] = 0.f;
    float cnt = 0.f;
#pragma unroll
    for (int i = 0; i < 4; ++i) {
      float e[32];
      encode_card32(c[i], val_emb, suit_emb, type_emb, e);
      if (mask[i]) {
#pragma unroll
        for (int j = 0; j < 32; ++j) emb[j] += e[j];
        cnt += 1.f;
      }
    }
    float invc = 1.f / fmaxf(cnt, 1.f);
#pragma unroll
    for (int j = 0; j < 32; ++j) sAct[tid][j] = hasv ? emb[j] * invc : 0.f;
    float t32[32];
#pragma unroll
    for (int j = 0; j < 32; ++j) {
      float acc = ce_b1[j];
#pragma unroll
      for (int k = 0; k < 6; ++k) acc += feats[k] * ce_w1[k * 32 + j];
      t32[j] = fmaxf(acc, 0.f);
    }
#pragma unroll
    for (int j = 0; j < 16; ++j) {
      float acc = ce_b2[j];
#pragma unroll
      for (int k = 0; k < 32; ++k) acc += t32[k] * ce_w2[k * 16 + j];
      sCombo[tid][j] = acc;
    }
    ws[1920 + tid] = total * 0.05f;
    ws[1950 + tid] = hasv ? 1.f : 0.f;
  }
  __syncthreads();
  for (int idx = tid; idx < 1920; idx += 256) {
    int a = idx >> 6, j = idx & 63;
    float acc = as_b1[j];
#pragma unroll
    for (int k = 0; k < 32; ++k) acc += sAct[a][k] * as_w1[(128 + k) * 64 + j];
#pragma unroll
    for (int k = 0; k < 16; ++k) acc += sCombo[a][k] * as_w1[(160 + k) * 64 + j];
    ws[idx] = acc;
  }
}

// ---------------------------------------------------------------------------
// Unified layer: QIN = quad-packed input (ds_read_b128, 4 k per read),
// else simple [k][64]. QOUT = quad-packed output. W read wave-uniformly.
// QIN loop unrolled x8 (32 k-values of scalar prefetch in flight).
// ---------------------------------------------------------------------------
template <int K, int NJ, bool RELU, bool HASB, bool QIN, bool QOUT>
__device__ __forceinline__ void layerU(
    const float* __restrict__ in, int inColBase, float* __restrict__ outB,
    int outColBase, const float* __restrict__ W, int ldw, int j0,
    const float* __restrict__ bias, int r) {
  float acc[NJ];
#pragma unroll
  for (int j = 0; j < NJ; ++j) acc[j] = HASB ? bias[j0 + j] : 0.f;
  if constexpr (QIN) {
    static_assert(K % 4 == 0, "quad input needs K%4==0");
    const int g0 = inColBase >> 2;
#pragma unroll 8
    for (int g = 0; g < K / 4; ++g) {
      float4 a = *(const float4*)&in[(g0 + g) * 256 + r * 4];
#pragma unroll
      for (int q = 0; q < 4; ++q) {
        float av = (q == 0) ? a.x : (q == 1) ? a.y : (q == 2) ? a.z : a.w;
        const float* wr = W + (size_t)(g * 4 + q) * ldw + j0;
#pragma unroll
        for (int j = 0; j < NJ; ++j) acc[j] += av * wr[j];
      }
    }
  } else {
#pragma unroll 4
    for (int k = 0; k < K; ++k) {
      float a = in[(inColBase + k) * 64 + r];
      const float* wr = W + (size_t)k * ldw + j0;
#pragma unroll
      for (int j = 0; j < NJ; ++j) acc[j] += a * wr[j];
    }
  }
#pragma unroll
  for (int j = 0; j < NJ; ++j) if (RELU) acc[j] = fmaxf(acc[j], 0.f);
  if constexpr (QOUT && (NJ % 4 == 0)) {
    const int c0 = outColBase + j0;      // quad-aligned by construction
#pragma unroll
    for (int qg = 0; qg < NJ / 4; ++qg) {
      float4 o = make_float4(acc[qg * 4], acc[qg * 4 + 1],
                             acc[qg * 4 + 2], acc[qg * 4 + 3]);
      *(float4*)&outB[((c0 >> 2) + qg) * 256 + r * 4] = o;
    }
  } else {
#pragma unroll
    for (int j = 0; j < NJ; ++j) outB[(outColBase + j0 + j) * 64 + r] = acc[j];
  }
}

// ---------------------------------------------------------------------------
// Main kernel. 64 rows/block, 1024 threads (16 waves), grid 256.
// bufA (quad, 152 cols): [0:32) hand_ctx | [32:64) enemy | [64:96) strat_ctx |
//   [96:150) discard -> later h2 (128)
// bufB: rows [0:20) strat_in | [20:84) t64 | [84:116) V | 116 sLen
//   -> later quad h1 -> later P7 out: t1 quads 0..15 | P quads 16..31
// ---------------------------------------------------------------------------
__global__ __launch_bounds__(1024) void policy_main(
    const int* __restrict__ hand_cards, const int* __restrict__ enemy_card,
    const int* __restrict__ hand_size, const float* __restrict__ game_state,
    const float* __restrict__ discard,
    const float* __restrict__ val_emb, const float* __restrict__ suit_emb,
    const float* __restrict__ type_emb,
    const float* __restrict__ he_wv, const float* __restrict__ he_bv,
    const float* __restrict__ he_wo, const float* __restrict__ he_bo,
    const float* __restrict__ se_w1, const float* __restrict__ se_b1,
    const float* __restrict__ se_w2, const float* __restrict__ se_b2,
    const float* __restrict__ atc_w2, const float* __restrict__ atc_b2,
    const float* __restrict__ as_w2, const float* __restrict__ as_b2,
    const float* __restrict__ as_w3, const float* __restrict__ as_b3,
    const float* __restrict__ cx_w1, const float* __restrict__ cx_b1,
    const float* __restrict__ cx_w2, const float* __restrict__ cx_b2,
    const float* __restrict__ ws, float* __restrict__ out) {
  __shared__ float bufA[38 * 256];   // 38 quad groups = 152 cols, 38 KB
  __shared__ float bufB[128 * 64];   // 32 KB

  const int tid = threadIdx.x;
  const int r = tid & 63;                                   // lane = batch row
  const int wq = __builtin_amdgcn_readfirstlane(tid >> 6);  // wave id 0..15
  const int b0 = blockIdx.x * 64;

  // ---------------- P0: staging + per-row features --------------------------
  for (int idx = tid; idx < 64 * 54; idx += 1024) {          // discard -> bufA
    int rr = idx / 54, k = idx - rr * 54;
    int c = 96 + k;
    bufA[(c >> 2) * 256 + rr * 4 + (c & 3)] = discard[(size_t)b0 * 54 + idx];
  }
  if (wq == 2) {                                            // game_state rows 0..9
#pragma unroll
    for (int k = 0; k < 10; ++k)
      bufB[k * 64 + r] = game_state[(size_t)(b0 + r) * 10 + k];
  }
  if (wq == 0) {                                            // hand features rows 10..19
    const int b = b0 + r;
    const float hsz = (float)hand_size[b];
    int aces = 0, faces = 0, low = 0, c1 = 0, c2 = 0, c3 = 0, c4 = 0;
#pragma unroll
    for (int i = 0; i < 8; ++i) {
      int c = hand_cards[b * 8 + i];
      int v = (c == 0) ? 0 : ((c - 1) % 13 + 1);
      int s = (c == 0) ? 0 : ((c - 1) / 13 + 1);
      aces += (v == 1);
      faces += (v >= 11 && v <= 13);
      low += (v >= 2 && v <= 6);
      c1 += (s == 1); c2 += (s == 2); c3 += (s == 3); c4 += (s == 4);
    }
    float sdiv = (float)((c1 > 0) + (c2 > 0) + (c3 > 0) + (c4 > 0)) * 0.25f;
    float hvr = (float)faces / (hsz + 1e-8f);
    bufB[(10 + 0) * 64 + r] = hsz;          bufB[(10 + 1) * 64 + r] = (float)aces;
    bufB[(10 + 2) * 64 + r] = (float)faces; bufB[(10 + 3) * 64 + r] = (float)low;
    bufB[(10 + 4) * 64 + r] = (float)c1;    bufB[(10 + 5) * 64 + r] = (float)c2;
    bufB[(10 + 6) * 64 + r] = (float)c3;    bufB[(10 + 7) * 64 + r] = (float)c4;
    bufB[(10 + 8) * 64 + r] = hvr;          bufB[(10 + 9) * 64 + r] = sdiv;
  }
  if (wq == 1) {                                            // enemy (quad) + sLen
    const int b = b0 + r;
    bufB[116 * 64 + r] = 8.0f / fmaxf((float)hand_size[b], 1.0f);
    float e[32];
    encode_card32(enemy_card[b], val_emb, suit_emb, type_emb, e);
#pragma unroll
    for (int g = 0; g < 8; ++g) {
      float4 ev = make_float4(e[g * 4], e[g * 4 + 1], e[g * 4 + 2], e[g * 4 + 3]);
      *(float4*)&bufA[(8 + g) * 256 + r * 4] = ev;   // cols 32..63
    }
  }
  __syncthreads();

  // ---------------- Phase A (task-parallel): se L1 | V -----------------------
  if (wq < 8) {
    layerU<20, 8, true, true, false, false>(bufB, 0, bufB, 20, se_w1, 64,
                                            wq * 8, se_b1, r);
  } else {
    layerU<32, 4, false, true, true, false>(bufA, 32, bufB, 84, he_wv, 32,
                                            (wq - 8) * 4, he_bv, r);
  }
  __syncthreads();

  // ---------------- Phase B (task-parallel): se L2 | hand_ctx ----------------
  if (wq < 8) {
    layerU<64, 4, false, true, false, true>(bufB, 20, bufA, 64, se_w2, 32,
                                            wq * 4, se_b2, r);
  } else {
    const int j0 = (wq - 8) * 4;
    float acc[4];
#pragma unroll
    for (int j = 0; j < 4; ++j) acc[j] = he_bo[j0 + j];
#pragma unroll 4
    for (int k = 0; k < 32; ++k) {
      float a = bufB[(84 + k) * 64 + r];
      const float* wr = he_wo + (size_t)k * 32 + j0;
#pragma unroll
      for (int j = 0; j < 4; ++j) acc[j] += a * wr[j];
    }
    float scale = bufB[116 * 64 + r];
    float4 o = make_float4(scale * acc[0], scale * acc[1],
                           scale * acc[2], scale * acc[3]);
    *(float4*)&bufA[(j0 >> 2) * 256 + r * 4] = o;
  }
  __syncthreads();

  // ---------------- L1: 150->128 relu, all input in LDS (37 quads + tail) ----
  {
    const int j0 = wq * 8;
    float acc[8];
#pragma unroll
    for (int j = 0; j < 8; ++j) acc[j] = cx_b1[j0 + j];
#pragma unroll 8
    for (int g = 0; g < 37; ++g) {
      float4 a = *(const float4*)&bufA[g * 256 + r * 4];
#pragma unroll
      for (int q = 0; q < 4; ++q) {
        float av = (q == 0) ? a.x : (q == 1) ? a.y : (q == 2) ? a.z : a.w;
        const float* wr = cx_w1 + (size_t)(g * 4 + q) * 128 + j0;
#pragma unroll
        for (int j = 0; j < 8; ++j) acc[j] += av * wr[j];
      }
    }
    {  // tail: cols 148,149 (discard elements 52,53)
      float4 a = *(const float4*)&bufA[37 * 256 + r * 4];
      const float* wr0 = cx_w1 + (size_t)148 * 128 + j0;
      const float* wr1 = cx_w1 + (size_t)149 * 128 + j0;
#pragma unroll
      for (int j = 0; j < 8; ++j) acc[j] += a.x * wr0[j] + a.y * wr1[j];
    }
#pragma unroll
    for (int qg = 0; qg < 2; ++qg) {
      float4 o = make_float4(fmaxf(acc[qg * 4], 0.f), fmaxf(acc[qg * 4 + 1], 0.f),
                             fmaxf(acc[qg * 4 + 2], 0.f), fmaxf(acc[qg * 4 + 3], 0.f));
      *(float4*)&bufB[((j0 >> 2) + qg) * 256 + r * 4] = o;   // h1 quad
    }
  }
  __syncthreads();

  // ---------------- L2: 128->128 relu  (bufB quad -> bufA quad = h2) --------
  layerU<128, 8, true, true, true, true>(bufB, 0, bufA, 0, cx_w2, 128, wq * 8,
                                         cx_b2, r);
  __syncthreads();

  // ---------------- P7 (L3 folded): t1 | P from h2  (bufA -> bufB) ----------
  if (wq < 8) {
    layerU<128, 8, true, true, true, true>(bufA, 0, bufB, 0, ws + 2048, 64,
                                           wq * 8, ws + 10240, r);
  } else {
    layerU<128, 8, false, true, true, true>(bufA, 0, bufB, 64, ws + 10304, 64,
                                            (wq - 8) * 8, ws + 18496, r);
  }
  __syncthreads();

  // ---------------- P9: scoring (logits per-wave from t1; P from bufB) ------
  if (wq < 15) {
    float lg0 = atc_b2[0], lg1 = atc_b2[1], lg2 = atc_b2[2], lg3 = atc_b2[3];
#pragma unroll 4
    for (int g = 0; g < 16; ++g) {            // t1 = bufB quad groups 0..15
      float4 t = *(const float4*)&bufB[g * 256 + r * 4];
#pragma unroll
      for (int q = 0; q < 4; ++q) {
        float tv = (q == 0) ? t.x : (q == 1) ? t.y : (q == 2) ? t.z : t.w;
        const float* wr = atc_w2 + (size_t)(g * 4 + q) * 4;
        lg0 += tv * wr[0]; lg1 += tv * wr[1];
        lg2 += tv * wr[2]; lg3 += tv * wr[3];
      }
    }
    float m = fmaxf(fmaxf(lg0, lg1), fmaxf(lg2, lg3));
    float e0 = expf(lg0 - m), e1 = expf(lg1 - m), e2 = expf(lg2 - m), e3 = expf(lg3 - m);
    float inv = 1.f / (e0 + e1 + e2 + e3);
    float tp0 = e0 * inv, tp1 = e1 * inv, tp3 = e3 * inv;

    const float b3v = as_b3[0];
#pragma unroll 1
    for (int i = 0; i < 2; ++i) {
      const int a = wq * 2 + i;                // wave-uniform
      const float* qa = ws + a * 64;           // uniform -> s_load
      float acc[32];
#pragma unroll
      for (int j = 0; j < 32; ++j) acc[j] = 0.f;
#pragma unroll 4
      for (int g = 0; g < 16; ++g) {           // P = bufB quad groups 16..31
        float4 pv = *(const float4*)&bufB[(16 + g) * 256 + r * 4];
#pragma unroll
        for (int q = 0; q < 4; ++q) {
          float p = (q == 0) ? pv.x : (q == 1) ? pv.y : (q == 2) ? pv.z : pv.w;
          const int k = g * 4 + q;
          float s = fmaxf(p + qa[k], 0.f);
          const float* w2r = as_w2 + (size_t)k * 32;
#pragma unroll
          for (int j = 0; j < 32; ++j) acc[j] += s * w2r[j];
        }
      }
      float sc = b3v;
#pragma unroll
      for (int j = 0; j < 32; ++j)
        sc += fmaxf(acc[j] + as_b2[j], 0.f) * as_w3[j];
      float st = ws[1920 + a], hv = ws[1950 + a];
      float bon = (hv > 0.5f) ? (tp0 * st + tp1 * (1.f - st)) : tp3 * 2.f;
      out[(size_t)(b0 + r) * 30 + a] = sc + bon;
    }
  }
}

// ---------------------------------------------------------------------------
extern "C" void kernel_launch(void* const* d_in, const int* in_sizes, int n_in,
                              void* d_out, int out_size, void* d_ws, size_t ws_size,
                              hipStream_t stream) {
  (void)in_sizes; (void)n_in; (void)out_size; (void)ws_size;
  const int* hand_cards = (const int*)d_in[0];
  const int* enemy_card = (const int*)d_in[1];
  const int* hand_size = (const int*)d_in[2];
  const float* game_state = (const float*)d_in[3];
  const float* discard = (const float*)d_in[4];
  const int* acards = (const int*)d_in[5];
  // d_in[6] = num_valid_actions (unused scalar)
  const float* val_emb = (const float*)d_in[7];
  const float* suit_emb = (const float*)d_in[8];
  const float* type_emb = (const float*)d_in[9];
  const float* ce_w1 = (const float*)d_in[10], * ce_b1 = (const float*)d_in[11];
  const float* ce_w2 = (const float*)d_in[12], * ce_b2 = (const float*)d_in[13];
  // d_in[14..21] = ha_* (hand self-attention) -- provably dead code, unused
  const float* he_wv = (const float*)d_in[26], * he_bv = (const float*)d_in[27];
  const float* he_wo = (const float*)d_in[28], * he_bo = (const float*)d_in[29];
  const float* se_w1 = (const float*)d_in[30], * se_b1 = (const float*)d_in[31];
  const float* se_w2 = (const float*)d_in[32], * se_b2 = (const float*)d_in[33];
  const float* atc_w1 = (const float*)d_in[34], * atc_b1 = (const float*)d_in[35];
  const float* atc_w2 = (const float*)d_in[36], * atc_b2 = (const float*)d_in[37];
  const float* as_w1 = (const float*)d_in[38], * as_b1 = (const float*)d_in[39];
  const float* as_w2 = (const float*)d_in[40], * as_b2 = (const float*)d_in[41];
  const float* as_w3 = (const float*)d_in[42], * as_b3 = (const float*)d_in[43];
  const float* cx_w1 = (const float*)d_in[44], * cx_b1 = (const float*)d_in[45];
  const float* cx_w2 = (const float*)d_in[46], * cx_b2 = (const float*)d_in[47];
  const float* cx_w3 = (const float*)d_in[48], * cx_b3 = (const float*)d_in[49];
  float* ws = (float*)d_ws;
  float* out = (float*)d_out;

  hipLaunchKernelGGL(precompute_kernel, dim3(33), dim3(256), 0, stream,
                     acards, val_emb, suit_emb, type_emb,
                     ce_w1, ce_b1, ce_w2, ce_b2, as_w1, as_b1,
                     cx_w3, cx_b3, atc_w1, atc_b1, ws);
  hipLaunchKernelGGL(policy_main, dim3(256), dim3(1024), 0, stream,
                     hand_cards, enemy_card, hand_size, game_state, discard,
                     val_emb, suit_emb, type_emb,
                     he_wv, he_bv, he_wo, he_bo,
                     se_w1, se_b1, se_w2, se_b2,
                     atc_w2, atc_b2,
                     as_w2, as_b2, as_w3, as_b3,
                     cx_w1, cx_b1, cx_w2, cx_b2,
                     ws, out);
}